// Round 12
// baseline (445.784 us; speedup 1.0000x reference)
//
#include <hip/hip_runtime.h>
#include <stdint.h>

#define N_NODES 4096
#define F_DIM   64
#define LRELU_ALPHA 0.2f

typedef _Float16 f16;
typedef __attribute__((ext_vector_type(8))) _Float16 half8;  // MFMA f16 A/B frag (4 VGPRs)
typedef __attribute__((ext_vector_type(4))) float f32x4;     // MFMA C/D frag

// ---------------------------------------------------------------------------
// Kernel 0: pack adj>0 into bitmasks, reading adj SEQUENTIALLY.
// bits[row*128 + jw] bit (j&31) = adj[row][j] > 0, row = b*4096+i, jw = j>>5.
// Thread -> one dword (32 j's, 8 int4 loads). Wave footprint per load
// instruction = 64 lanes x 16B at 128B stride = one contiguous 8KB run,
// fully consumed across the 8 loads -> DRAM-page-sequential (fills hit
// 6.6 TB/s on this pattern; attn's old 16-row-scattered reads could not).
// grid 8192 x 256 covers 2M dwords.
// ---------------------------------------------------------------------------
__global__ __launch_bounds__(256) void gat_pack(
    const int* __restrict__ adj, uint32_t* __restrict__ bits)
{
  const int idx = blockIdx.x * 256 + threadIdx.x;   // dword index
  const int r   = idx >> 7;                         // global row
  const int jw  = idx & 127;
  const int* p = adj + (size_t)r * N_NODES + jw * 32;
  uint32_t mask = 0;
#pragma unroll
  for (int k = 0; k < 8; ++k) {
    const int4 v = *(const int4*)(p + k * 4);
    mask |= (v.x > 0 ? 1u : 0u) << (k * 4 + 0);
    mask |= (v.y > 0 ? 1u : 0u) << (k * 4 + 1);
    mask |= (v.z > 0 ? 1u : 0u) << (k * 4 + 2);
    mask |= (v.w > 0 ? 1u : 0u) << (k * 4 + 3);
  }
  bits[idx] = mask;
}

// ---------------------------------------------------------------------------
// Kernel 1: Wh = h@W (fp32 VALU); ei=Wh·a1, ej=Wh·a2; wh16[b][f][n] = (f16)Wh
// (transposed via LDS for coalesced stores); blockmax = per-block max ej.
// grid 1024 x 256; wave = 4 rows. [unchanged from the proven anchor]
// ---------------------------------------------------------------------------
__global__ __launch_bounds__(256) void gat_prep(
    const float* __restrict__ h, const float* __restrict__ W,
    const float* __restrict__ a, float* __restrict__ ei,
    float* __restrict__ ej, f16* __restrict__ wh16,
    float* __restrict__ blockmax)
{
  __shared__ float sh_h[4][F_DIM];
  __shared__ f16 tile[F_DIM][16];   // [f][local n]
  __shared__ float wmax[4];
  const int t = threadIdx.x, w = t >> 6, lane = t & 63;
  const int n0 = blockIdx.x * 16;       // global row base (0..16383)
  const int b  = n0 >> 12;
  const int nl0 = n0 & (N_NODES - 1);   // row base within batch

  float wcol[F_DIM];
#pragma unroll
  for (int k = 0; k < F_DIM; ++k) wcol[k] = W[k * F_DIM + lane];
  const float a1 = a[lane], a2 = a[F_DIM + lane];

  float runmax = -3e38f;
  for (int r = 0; r < 4; ++r) {
    const int loc = w * 4 + r;
    const int n = n0 + loc;
    const float hv = h[(size_t)n * F_DIM + lane];
    sh_h[w][lane] = hv;                       // same-wave LDS write->read (in-order pipe)
    float wh = 0.f;
#pragma unroll
    for (int k = 0; k < F_DIM; k += 4) {
      const float4 hb = *(const float4*)(&sh_h[w][k]);
      wh = fmaf(hb.x, wcol[k + 0], wh);
      wh = fmaf(hb.y, wcol[k + 1], wh);
      wh = fmaf(hb.z, wcol[k + 2], wh);
      wh = fmaf(hb.w, wcol[k + 3], wh);
    }
    float s1 = wh * a1, s2 = wh * a2;
#pragma unroll
    for (int off = 32; off; off >>= 1) {
      s1 += __shfl_xor(s1, off);
      s2 += __shfl_xor(s2, off);
    }
    if (lane == 0) { ei[n] = s1; ej[n] = s2; }
    runmax = fmaxf(runmax, s2);               // s2 identical on all lanes
    tile[lane][loc] = (f16)wh;                // f = lane
  }
  if (lane == 0) wmax[w] = runmax;
  __syncthreads();

  // coalesced f16 store: thread t -> f = t>>2, 8B chunk part = t&3
  {
    const int f = t >> 2, part = t & 3;
    *(uint2*)(wh16 + ((size_t)(b * F_DIM + f)) * N_NODES + nl0 + part * 4) =
        *(const uint2*)(&tile[f][part * 4]);
  }
  if (t == 0)
    blockmax[blockIdx.x] =
        fmaxf(fmaxf(wmax[0], wmax[1]), fmaxf(wmax[2], wmax[3]));
}

// ---------------------------------------------------------------------------
// Kernel 2: fused masked-softmax attention + PV (f16 MFMA) + ELU, direct out.
// block = (b, 16-row i-tile), 512 threads = 8 waves; wave w sweeps j in
// [w*512, (w+1)*512). DELTA vs R10: adjacency comes from the packed bitmask
// (one uint4 per 4 iters per lane, 16 distinct addrs/wave, L2-hot) instead
// of the 16-row-scattered 2KB/iter int4 loads that thrashed DRAM pages.
// Bit for j: dword (row*128 + j>>5), bit j&31; here j = w*512 + jc*32 +
// quad*8 + x -> dword w*16+jc, bit quad*8+x.
// Range control: p' = exp(leaky(e) - bnd), bnd = leaky(ei + maxej_batch)
// >= row max (leaky monotone) -> p' in (0,1], f16-safe; shift cancels in
// num/den. A-frag: A[m=lane&15][k=quad*8+x]; B-frag: B[k][n=lane&15];
// C/D: row=quad*4+reg, col=lane&15 (HW-verified m89/m91).
// ---------------------------------------------------------------------------
__global__ __launch_bounds__(512, 6) void gat_attn(
    const uint32_t* __restrict__ bits, const float* __restrict__ ei,
    const float* __restrict__ ej, const f16* __restrict__ wh16,
    const float* __restrict__ blockmax, float* __restrict__ out)
{
  __shared__ float num_lds[8][16][F_DIM];   // 32 KB
  __shared__ float den_lds[8][16];          // 512 B

  const int t = threadIdx.x, w = t >> 6, lane = t & 63;
  const int quad = lane >> 4, m = lane & 15;
  const int b  = blockIdx.x >> 8;            // 256 i-tiles per batch
  const int i0 = (blockIdx.x & 255) * 16;
  const int i  = i0 + m;
  const int rowg = b * N_NODES + i;

  // per-batch max(ej): reduce 256 plain-stored per-block maxima (L2-hot)
  float maxej;
  {
    const float4 v = *(const float4*)(blockmax + b * 256 + lane * 4);
    maxej = fmaxf(fmaxf(v.x, v.y), fmaxf(v.z, v.w));
#pragma unroll
    for (int off = 32; off; off >>= 1)
      maxej = fmaxf(maxej, __shfl_xor(maxej, off));
  }

  const float ei_s = ei[rowg];
  float bnd = ei_s + maxej;
  bnd = fmaxf(bnd, LRELU_ALPHA * bnd);       // leaky(ei + maxej) >= row max logit

  const float* ejb     = ej + b * N_NODES;
  const uint32_t* bitrow = bits + (size_t)rowg * 128 + w * 16;
  const f16*   whb     = wh16 + ((size_t)(b * F_DIM + m)) * N_NODES;

  f32x4 acc[4] = {{0.f,0.f,0.f,0.f},{0.f,0.f,0.f,0.f},
                  {0.f,0.f,0.f,0.f},{0.f,0.f,0.f,0.f}};
  float den = 0.f;
  const int jbase = w * (N_NODES / 8);       // this wave's 512-j window

  for (int jo = 0; jo < 4; ++jo) {
    const uint4 dq = *(const uint4*)(bitrow + jo * 4);
    const uint32_t dws[4] = {dq.x, dq.y, dq.z, dq.w};

#pragma unroll
    for (int ji = 0; ji < 4; ++ji) {
      const int jc = jo * 4 + ji;
      const int jk = jbase + jc * 32 + quad * 8;
      const uint32_t dw = dws[ji];

      float ejA[8];
      *(float4*)(&ejA[0]) = *(const float4*)(ejb + jk);
      *(float4*)(&ejA[4]) = *(const float4*)(ejb + jk + 4);

      half8 bf[4];
#pragma unroll
      for (int fc = 0; fc < 4; ++fc)
        bf[fc] = *(const half8*)(whb + (size_t)(fc * 16) * N_NODES + jk);

      half8 pa;
#pragma unroll
      for (int x = 0; x < 8; ++x) {
        float e = ei_s + ejA[x];
        e = fmaxf(e, LRELU_ALPHA * e);
        const float p =
            ((dw >> (quad * 8 + x)) & 1u) ? __expf(e - bnd) : 0.f;
        pa[x] = (f16)p;
        den += (float)pa[x];   // accumulate the SAME quantized value MFMA sees
      }

#pragma unroll
      for (int fc = 0; fc < 4; ++fc)
        acc[fc] = __builtin_amdgcn_mfma_f32_16x16x32_f16(pa, bf[fc], acc[fc], 0, 0, 0);
    }
  }

  // den: lanes sharing a row (same lane&15) live 16 apart
  den += __shfl_xor(den, 16);
  den += __shfl_xor(den, 32);
  if (lane < 16) den_lds[w][lane] = den;

#pragma unroll
  for (int fc = 0; fc < 4; ++fc)
#pragma unroll
    for (int rg = 0; rg < 4; ++rg)
      num_lds[w][quad * 4 + rg][fc * 16 + m] = acc[fc][rg];
  __syncthreads();

  // merge 8 wave-partials, divide, ELU, coalesced store (1024 outs, 512 thr)
#pragma unroll
  for (int k = 0; k < 2; ++k) {
    const int idx = k * 512 + t;
    const int il = idx >> 6, f = idx & 63;
    float num = 0.f, d = 0.f;
#pragma unroll
    for (int ww = 0; ww < 8; ++ww) {
      num += num_lds[ww][il][f];
      d   += den_lds[ww][il];
    }
    float v = (d > 0.f) ? (num / d) : 0.f;
    v = (v > 0.f) ? v : expm1f(v);
    out[((size_t)(b * N_NODES + i0 + il)) * F_DIM + f] = v;
  }
}

extern "C" void kernel_launch(void* const* d_in, const int* in_sizes, int n_in,
                              void* d_out, int out_size, void* d_ws, size_t ws_size,
                              hipStream_t stream) {
  const float* h   = (const float*)d_in[0];
  const int*   adj = (const int*)d_in[1];
  const float* W   = (const float*)d_in[2];
  const float* a   = (const float*)d_in[3];
  float* out = (float*)d_out;

  char* ws = (char*)d_ws;
  // Workspace (~10.2 MB):
  // [0,       +64 KB)  ei
  // [65536,   +64 KB)  ej
  // [131072,  +4 KB)   blockmax (1024 floats, fully written by gat_prep)
  // [135168,  +2 MB)   wh16
  // [2232320, +8 MB)   bits (2M dwords, fully written by gat_pack)
  float*    ei       = (float*)ws;
  float*    ej       = (float*)(ws + 65536);
  float*    blockmax = (float*)(ws + 131072);
  f16*      wh16     = (f16*)(ws + 135168);
  uint32_t* bits     = (uint32_t*)(ws + 2232320);

  hipLaunchKernelGGL(gat_pack, dim3(8192), dim3(256), 0, stream, adj, bits);
  hipLaunchKernelGGL(gat_prep, dim3(1024), dim3(256), 0, stream,
                     h, W, a, ei, ej, wh16, blockmax);
  hipLaunchKernelGGL(gat_attn, dim3(1024), dim3(512), 0, stream,
                     bits, ei, ej, wh16, blockmax, out);
}

// Round 13
// 444.528 us; speedup vs baseline: 1.0028x; 1.0028x over previous
//
#include <hip/hip_runtime.h>
#include <stdint.h>

#define N_NODES 4096
#define F_DIM   64
#define LRELU_ALPHA 0.2f

typedef _Float16 f16;
typedef __attribute__((ext_vector_type(8))) _Float16 half8;  // MFMA f16 A/B frag (4 VGPRs)
typedef __attribute__((ext_vector_type(4))) float f32x4;     // MFMA C/D frag

// ---------------------------------------------------------------------------
// Kernel 0 (REWRITTEN): ballot-pack adj>0 into bitmasks, fully coalesced.
// Lane i loads ONE int at j0+i -> wave instruction = 256 B contiguous,
// every byte consumed (R12's version had 64 lanes at 128-B stride = 64
// distinct lines/instr, 4x the address work -> the regression).
// __ballot(v>0) bit i <-> j0+i, so the uint64 little-endian store at dword
// index j0>>5 reproduces EXACTLY the layout attn already reads:
// bits[row*128 + (j>>5)] bit (j&31). block = one row (16 KB contiguous);
// wave w covers j in [w*1024,(w+1)*1024) as 16 fully-unrolled independent
// loads (4 KB in flight/wave). grid 16384 x 256.
// ---------------------------------------------------------------------------
__global__ __launch_bounds__(256) void gat_pack(
    const int* __restrict__ adj, uint32_t* __restrict__ bits)
{
  const int t = threadIdx.x, w = t >> 6, lane = t & 63;
  const int r = blockIdx.x;                       // global row (0..16383)
  const int* row = adj + (size_t)r * N_NODES;
  const int jw0 = w * 1024;

  int v[16];
#pragma unroll
  for (int p = 0; p < 16; ++p)
    v[p] = row[jw0 + p * 64 + lane];              // 16 loads in flight

#pragma unroll
  for (int p = 0; p < 16; ++p) {
    const unsigned long long m = __ballot(v[p] > 0);
    if (lane == 0)
      *(uint64_t*)(bits + (size_t)r * 128 + ((jw0 + p * 64) >> 5)) = m;
  }
}

// ---------------------------------------------------------------------------
// Kernel 1: Wh = h@W (fp32 VALU); ei=Wh·a1, ej=Wh·a2; wh16[b][f][n] = (f16)Wh
// (transposed via LDS for coalesced stores); blockmax = per-block max ej.
// grid 1024 x 256; wave = 4 rows. [unchanged from the proven anchor]
// ---------------------------------------------------------------------------
__global__ __launch_bounds__(256) void gat_prep(
    const float* __restrict__ h, const float* __restrict__ W,
    const float* __restrict__ a, float* __restrict__ ei,
    float* __restrict__ ej, f16* __restrict__ wh16,
    float* __restrict__ blockmax)
{
  __shared__ float sh_h[4][F_DIM];
  __shared__ f16 tile[F_DIM][16];   // [f][local n]
  __shared__ float wmax[4];
  const int t = threadIdx.x, w = t >> 6, lane = t & 63;
  const int n0 = blockIdx.x * 16;       // global row base (0..16383)
  const int b  = n0 >> 12;
  const int nl0 = n0 & (N_NODES - 1);   // row base within batch

  float wcol[F_DIM];
#pragma unroll
  for (int k = 0; k < F_DIM; ++k) wcol[k] = W[k * F_DIM + lane];
  const float a1 = a[lane], a2 = a[F_DIM + lane];

  float runmax = -3e38f;
  for (int r = 0; r < 4; ++r) {
    const int loc = w * 4 + r;
    const int n = n0 + loc;
    const float hv = h[(size_t)n * F_DIM + lane];
    sh_h[w][lane] = hv;                       // same-wave LDS write->read (in-order pipe)
    float wh = 0.f;
#pragma unroll
    for (int k = 0; k < F_DIM; k += 4) {
      const float4 hb = *(const float4*)(&sh_h[w][k]);
      wh = fmaf(hb.x, wcol[k + 0], wh);
      wh = fmaf(hb.y, wcol[k + 1], wh);
      wh = fmaf(hb.z, wcol[k + 2], wh);
      wh = fmaf(hb.w, wcol[k + 3], wh);
    }
    float s1 = wh * a1, s2 = wh * a2;
#pragma unroll
    for (int off = 32; off; off >>= 1) {
      s1 += __shfl_xor(s1, off);
      s2 += __shfl_xor(s2, off);
    }
    if (lane == 0) { ei[n] = s1; ej[n] = s2; }
    runmax = fmaxf(runmax, s2);               // s2 identical on all lanes
    tile[lane][loc] = (f16)wh;                // f = lane
  }
  if (lane == 0) wmax[w] = runmax;
  __syncthreads();

  // coalesced f16 store: thread t -> f = t>>2, 8B chunk part = t&3
  {
    const int f = t >> 2, part = t & 3;
    *(uint2*)(wh16 + ((size_t)(b * F_DIM + f)) * N_NODES + nl0 + part * 4) =
        *(const uint2*)(&tile[f][part * 4]);
  }
  if (t == 0)
    blockmax[blockIdx.x] =
        fmaxf(fmaxf(wmax[0], wmax[1]), fmaxf(wmax[2], wmax[3]));
}

// ---------------------------------------------------------------------------
// Kernel 2: fused masked-softmax attention + PV (f16 MFMA) + ELU, direct out.
// block = (b, 16-row i-tile), 512 threads = 8 waves; wave w sweeps j in
// [w*512, (w+1)*512). Adjacency from packed bitmask (L2-hot after first
// touch; 8 KB/block). [unchanged from R12's passing source]
// Bit for j: dword (row*128 + j>>5), bit j&31; here j = w*512 + jc*32 +
// quad*8 + x -> dword w*16+jc, bit quad*8+x.
// Range control: p' = exp(leaky(e) - bnd), bnd = leaky(ei + maxej_batch)
// >= row max (leaky monotone) -> p' in (0,1], f16-safe; shift cancels in
// num/den. A-frag: A[m=lane&15][k=quad*8+x]; B-frag: B[k][n=lane&15];
// C/D: row=quad*4+reg, col=lane&15 (HW-verified m89/m91).
// ---------------------------------------------------------------------------
__global__ __launch_bounds__(512, 6) void gat_attn(
    const uint32_t* __restrict__ bits, const float* __restrict__ ei,
    const float* __restrict__ ej, const f16* __restrict__ wh16,
    const float* __restrict__ blockmax, float* __restrict__ out)
{
  __shared__ float num_lds[8][16][F_DIM];   // 32 KB
  __shared__ float den_lds[8][16];          // 512 B

  const int t = threadIdx.x, w = t >> 6, lane = t & 63;
  const int quad = lane >> 4, m = lane & 15;
  const int b  = blockIdx.x >> 8;            // 256 i-tiles per batch
  const int i0 = (blockIdx.x & 255) * 16;
  const int i  = i0 + m;
  const int rowg = b * N_NODES + i;

  // per-batch max(ej): reduce 256 plain-stored per-block maxima (L2-hot)
  float maxej;
  {
    const float4 v = *(const float4*)(blockmax + b * 256 + lane * 4);
    maxej = fmaxf(fmaxf(v.x, v.y), fmaxf(v.z, v.w));
#pragma unroll
    for (int off = 32; off; off >>= 1)
      maxej = fmaxf(maxej, __shfl_xor(maxej, off));
  }

  const float ei_s = ei[rowg];
  float bnd = ei_s + maxej;
  bnd = fmaxf(bnd, LRELU_ALPHA * bnd);       // leaky(ei + maxej) >= row max logit

  const float* ejb     = ej + b * N_NODES;
  const uint32_t* bitrow = bits + (size_t)rowg * 128 + w * 16;
  const f16*   whb     = wh16 + ((size_t)(b * F_DIM + m)) * N_NODES;

  f32x4 acc[4] = {{0.f,0.f,0.f,0.f},{0.f,0.f,0.f,0.f},
                  {0.f,0.f,0.f,0.f},{0.f,0.f,0.f,0.f}};
  float den = 0.f;
  const int jbase = w * (N_NODES / 8);       // this wave's 512-j window

  for (int jo = 0; jo < 4; ++jo) {
    const uint4 dq = *(const uint4*)(bitrow + jo * 4);
    const uint32_t dws[4] = {dq.x, dq.y, dq.z, dq.w};

#pragma unroll
    for (int ji = 0; ji < 4; ++ji) {
      const int jc = jo * 4 + ji;
      const int jk = jbase + jc * 32 + quad * 8;
      const uint32_t dw = dws[ji];

      float ejA[8];
      *(float4*)(&ejA[0]) = *(const float4*)(ejb + jk);
      *(float4*)(&ejA[4]) = *(const float4*)(ejb + jk + 4);

      half8 bf[4];
#pragma unroll
      for (int fc = 0; fc < 4; ++fc)
        bf[fc] = *(const half8*)(whb + (size_t)(fc * 16) * N_NODES + jk);

      half8 pa;
#pragma unroll
      for (int x = 0; x < 8; ++x) {
        float e = ei_s + ejA[x];
        e = fmaxf(e, LRELU_ALPHA * e);
        const float p =
            ((dw >> (quad * 8 + x)) & 1u) ? __expf(e - bnd) : 0.f;
        pa[x] = (f16)p;
        den += (float)pa[x];   // accumulate the SAME quantized value MFMA sees
      }

#pragma unroll
      for (int fc = 0; fc < 4; ++fc)
        acc[fc] = __builtin_amdgcn_mfma_f32_16x16x32_f16(pa, bf[fc], acc[fc], 0, 0, 0);
    }
  }

  // den: lanes sharing a row (same lane&15) live 16 apart
  den += __shfl_xor(den, 16);
  den += __shfl_xor(den, 32);
  if (lane < 16) den_lds[w][lane] = den;

#pragma unroll
  for (int fc = 0; fc < 4; ++fc)
#pragma unroll
    for (int rg = 0; rg < 4; ++rg)
      num_lds[w][quad * 4 + rg][fc * 16 + m] = acc[fc][rg];
  __syncthreads();

  // merge 8 wave-partials, divide, ELU, coalesced store (1024 outs, 512 thr)
#pragma unroll
  for (int k = 0; k < 2; ++k) {
    const int idx = k * 512 + t;
    const int il = idx >> 6, f = idx & 63;
    float num = 0.f, d = 0.f;
#pragma unroll
    for (int ww = 0; ww < 8; ++ww) {
      num += num_lds[ww][il][f];
      d   += den_lds[ww][il];
    }
    float v = (d > 0.f) ? (num / d) : 0.f;
    v = (v > 0.f) ? v : expm1f(v);
    out[((size_t)(b * N_NODES + i0 + il)) * F_DIM + f] = v;
  }
}

extern "C" void kernel_launch(void* const* d_in, const int* in_sizes, int n_in,
                              void* d_out, int out_size, void* d_ws, size_t ws_size,
                              hipStream_t stream) {
  const float* h   = (const float*)d_in[0];
  const int*   adj = (const int*)d_in[1];
  const float* W   = (const float*)d_in[2];
  const float* a   = (const float*)d_in[3];
  float* out = (float*)d_out;

  char* ws = (char*)d_ws;
  // Workspace (~10.2 MB):
  // [0,       +64 KB)  ei
  // [65536,   +64 KB)  ej
  // [131072,  +4 KB)   blockmax (1024 floats, fully written by gat_prep)
  // [135168,  +2 MB)   wh16
  // [2232320, +8 MB)   bits (2M dwords, fully written by gat_pack)
  float*    ei       = (float*)ws;
  float*    ej       = (float*)(ws + 65536);
  float*    blockmax = (float*)(ws + 131072);
  f16*      wh16     = (f16*)(ws + 135168);
  uint32_t* bits     = (uint32_t*)(ws + 2232320);

  hipLaunchKernelGGL(gat_pack, dim3(16384), dim3(256), 0, stream, adj, bits);
  hipLaunchKernelGGL(gat_prep, dim3(1024), dim3(256), 0, stream,
                     h, W, a, ei, ej, wh16, blockmax);
  hipLaunchKernelGGL(gat_attn, dim3(1024), dim3(512), 0, stream,
                     bits, ei, ej, wh16, blockmax, out);
}

// Round 15
// 403.689 us; speedup vs baseline: 1.1043x; 1.1012x over previous
//
#include <hip/hip_runtime.h>
#include <stdint.h>

#define N_NODES 4096
#define F_DIM   64
#define LRELU_ALPHA 0.2f

typedef _Float16 f16;
typedef __attribute__((ext_vector_type(8))) _Float16 half8;  // MFMA f16 A/B frag (4 VGPRs)
typedef __attribute__((ext_vector_type(4))) float f32x4;     // MFMA C/D frag

// ---------------------------------------------------------------------------
// Kernel 0: ballot-pack adj>0 into bitmasks, fully coalesced (proven R13).
// bits[row*128 + (j>>5)] bit (j&31) = adj[row][j] > 0.
// ---------------------------------------------------------------------------
__global__ __launch_bounds__(256) void gat_pack(
    const int* __restrict__ adj, uint32_t* __restrict__ bits)
{
  const int t = threadIdx.x, w = t >> 6, lane = t & 63;
  const int r = blockIdx.x;                       // global row (0..16383)
  const int* row = adj + (size_t)r * N_NODES;
  const int jw0 = w * 1024;

  int v[16];
#pragma unroll
  for (int p = 0; p < 16; ++p)
    v[p] = row[jw0 + p * 64 + lane];              // 16 loads in flight

#pragma unroll
  for (int p = 0; p < 16; ++p) {
    const unsigned long long m = __ballot(v[p] > 0);
    if (lane == 0)
      *(uint64_t*)(bits + (size_t)r * 128 + ((jw0 + p * 64) >> 5)) = m;
  }
}

// ---------------------------------------------------------------------------
// Kernel 1: Wh = h@W; ei=Wh·a1, ej=Wh·a2; Wh stored in MFMA B-FRAGMENT ORDER:
//   whB[((b*128+jc)*4+fc)*512 + (q*16+m)*8 + x] = Wh[j=jc*32+q*8+x][f=fc*16+m]
// STRIDE FIX vs R14: each (jc,fc) block is 32j x 16f = 512 f16 (R14 used
// 1024 -> whB ran 4 MB and overflowed into bits, corrupting masks for
// b>=2 -> absmax 0.377. Write/read were consistent so whB itself was fine.)
// Block = 16 rows => jc = nl0>>5 fixed, q in {q0, q0+1}, q0 = (nl0>>3)&3.
// Store map: t -> fc=t>>6, q'=(t&63)>>5, m=(t>>1)&15, xh=(t&1)*4; 8-B
// coalesced stores. blockmax unchanged.
// ---------------------------------------------------------------------------
__global__ __launch_bounds__(256) void gat_prep(
    const float* __restrict__ h, const float* __restrict__ W,
    const float* __restrict__ a, float* __restrict__ ei,
    float* __restrict__ ej, f16* __restrict__ whB,
    float* __restrict__ blockmax)
{
  __shared__ float sh_h[4][F_DIM];
  __shared__ f16 tile[F_DIM][16];   // [f][loc], loc = j - n0
  __shared__ float wmax[4];
  const int t = threadIdx.x, w = t >> 6, lane = t & 63;
  const int n0 = blockIdx.x * 16;       // global row base (0..16383)
  const int b  = n0 >> 12;
  const int nl0 = n0 & (N_NODES - 1);   // row base within batch

  float wcol[F_DIM];
#pragma unroll
  for (int k = 0; k < F_DIM; ++k) wcol[k] = W[k * F_DIM + lane];
  const float a1 = a[lane], a2 = a[F_DIM + lane];

  float runmax = -3e38f;
  for (int r = 0; r < 4; ++r) {
    const int loc = w * 4 + r;
    const int n = n0 + loc;
    const float hv = h[(size_t)n * F_DIM + lane];
    sh_h[w][lane] = hv;                       // same-wave LDS write->read (in-order pipe)
    float wh = 0.f;
#pragma unroll
    for (int k = 0; k < F_DIM; k += 4) {
      const float4 hb = *(const float4*)(&sh_h[w][k]);
      wh = fmaf(hb.x, wcol[k + 0], wh);
      wh = fmaf(hb.y, wcol[k + 1], wh);
      wh = fmaf(hb.z, wcol[k + 2], wh);
      wh = fmaf(hb.w, wcol[k + 3], wh);
    }
    float s1 = wh * a1, s2 = wh * a2;
#pragma unroll
    for (int off = 32; off; off >>= 1) {
      s1 += __shfl_xor(s1, off);
      s2 += __shfl_xor(s2, off);
    }
    if (lane == 0) { ei[n] = s1; ej[n] = s2; }
    runmax = fmaxf(runmax, s2);               // s2 identical on all lanes
    tile[lane][loc] = (f16)wh;                // f = lane
  }
  if (lane == 0) wmax[w] = runmax;
  __syncthreads();

  // B-fragment-order store (coalesced 8-B): jc/q0 fixed per block.
  {
    const int jc = nl0 >> 5;
    const int q0 = (nl0 >> 3) & 3;            // in {0, 2}
    const int fc = t >> 6;
    const int r6 = t & 63;
    const int qp = r6 >> 5;                   // q' in {0,1}
    const int m  = (r6 >> 1) & 15;
    const int xh = (t & 1) * 4;
    const int loc = qp * 8 + xh;              // source loc (+0..3)
    f16* dst = whB + (((size_t)(b * 128 + jc)) * 4 + fc) * 512
                   + ((q0 + qp) * 16 + m) * 8 + xh;
    *(uint2*)dst = *(const uint2*)(&tile[fc * 16 + m][loc]);
  }
  if (t == 0)
    blockmax[blockIdx.x] =
        fmaxf(fmaxf(wmax[0], wmax[1]), fmaxf(wmax[2], wmax[3]));
}

// ---------------------------------------------------------------------------
// Kernel 2: fused masked-softmax attention + PV (f16 MFMA) + ELU, direct out.
// block = (b, 16-row i-tile), 512 threads = 8 waves; wave w sweeps j in
// [w*512, (w+1)*512). bf fragments load from whB in lane-contiguous order
// (base + lane*16B: one contiguous 1-KB run per instruction) instead of the
// 16-lines-8KB-apart scatter of the wh16[b][f][n] layout. ej/bits/exp/
// LDS-merge identical to the R13 passing source; numerics bit-identical.
// Range control: p' = exp(leaky(e) - bnd), bnd = leaky(ei + maxej_batch)
// >= row max (leaky monotone) -> p' in (0,1], f16-safe; shift cancels in
// num/den. A-frag: A[m=lane&15][k=quad*8+x]; B-frag: B[k=quad*8+x][n=m];
// C/D: row=quad*4+reg, col=lane&15 (HW-verified m89/m91).
// ---------------------------------------------------------------------------
__global__ __launch_bounds__(512, 6) void gat_attn(
    const uint32_t* __restrict__ bits, const float* __restrict__ ei,
    const float* __restrict__ ej, const f16* __restrict__ whB,
    const float* __restrict__ blockmax, float* __restrict__ out)
{
  __shared__ float num_lds[8][16][F_DIM];   // 32 KB
  __shared__ float den_lds[8][16];          // 512 B

  const int t = threadIdx.x, w = t >> 6, lane = t & 63;
  const int quad = lane >> 4, m = lane & 15;
  const int b  = blockIdx.x >> 8;            // 256 i-tiles per batch
  const int i0 = (blockIdx.x & 255) * 16;
  const int i  = i0 + m;
  const int rowg = b * N_NODES + i;

  // per-batch max(ej): reduce 256 plain-stored per-block maxima (L2-hot)
  float maxej;
  {
    const float4 v = *(const float4*)(blockmax + b * 256 + lane * 4);
    maxej = fmaxf(fmaxf(v.x, v.y), fmaxf(v.z, v.w));
#pragma unroll
    for (int off = 32; off; off >>= 1)
      maxej = fmaxf(maxej, __shfl_xor(maxej, off));
  }

  const float ei_s = ei[rowg];
  float bnd = ei_s + maxej;
  bnd = fmaxf(bnd, LRELU_ALPHA * bnd);       // leaky(ei + maxej) >= row max logit

  const float* ejb     = ej + b * N_NODES;
  const uint32_t* bitrow = bits + (size_t)rowg * 128 + w * 16;
  // this wave's fragment base: chunk jc_g = w*16 + jc; 2048 f16 per chunk
  const f16* whw = whB + ((size_t)(b * 128 + w * 16)) * 2048 + lane * 8;

  f32x4 acc[4] = {{0.f,0.f,0.f,0.f},{0.f,0.f,0.f,0.f},
                  {0.f,0.f,0.f,0.f},{0.f,0.f,0.f,0.f}};
  float den = 0.f;
  const int jbase = w * (N_NODES / 8);       // this wave's 512-j window

  for (int jo = 0; jo < 4; ++jo) {
    const uint4 dq = *(const uint4*)(bitrow + jo * 4);
    const uint32_t dws[4] = {dq.x, dq.y, dq.z, dq.w};

#pragma unroll
    for (int ji = 0; ji < 4; ++ji) {
      const int jc = jo * 4 + ji;
      const int jk = jbase + jc * 32 + quad * 8;
      const uint32_t dw = dws[ji];

      float ejA[8];
      *(float4*)(&ejA[0]) = *(const float4*)(ejb + jk);
      *(float4*)(&ejA[4]) = *(const float4*)(ejb + jk + 4);

      const f16* wjc = whw + (size_t)jc * 2048;
      half8 bf[4];
#pragma unroll
      for (int fc = 0; fc < 4; ++fc)
        bf[fc] = *(const half8*)(wjc + fc * 512);

      half8 pa;
#pragma unroll
      for (int x = 0; x < 8; ++x) {
        float e = ei_s + ejA[x];
        e = fmaxf(e, LRELU_ALPHA * e);
        const float p =
            ((dw >> (quad * 8 + x)) & 1u) ? __expf(e - bnd) : 0.f;
        pa[x] = (f16)p;
        den += (float)pa[x];   // accumulate the SAME quantized value MFMA sees
      }

#pragma unroll
      for (int fc = 0; fc < 4; ++fc)
        acc[fc] = __builtin_amdgcn_mfma_f32_16x16x32_f16(pa, bf[fc], acc[fc], 0, 0, 0);
    }
  }

  // den: lanes sharing a row (same lane&15) live 16 apart
  den += __shfl_xor(den, 16);
  den += __shfl_xor(den, 32);
  if (lane < 16) den_lds[w][lane] = den;

#pragma unroll
  for (int fc = 0; fc < 4; ++fc)
#pragma unroll
    for (int rg = 0; rg < 4; ++rg)
      num_lds[w][quad * 4 + rg][fc * 16 + m] = acc[fc][rg];
  __syncthreads();

  // merge 8 wave-partials, divide, ELU, coalesced store (1024 outs, 512 thr)
#pragma unroll
  for (int k = 0; k < 2; ++k) {
    const int idx = k * 512 + t;
    const int il = idx >> 6, f = idx & 63;
    float num = 0.f, d = 0.f;
#pragma unroll
    for (int ww = 0; ww < 8; ++ww) {
      num += num_lds[ww][il][f];
      d   += den_lds[ww][il];
    }
    float v = (d > 0.f) ? (num / d) : 0.f;
    v = (v > 0.f) ? v : expm1f(v);
    out[((size_t)(b * N_NODES + i0 + il)) * F_DIM + f] = v;
  }
}

extern "C" void kernel_launch(void* const* d_in, const int* in_sizes, int n_in,
                              void* d_out, int out_size, void* d_ws, size_t ws_size,
                              hipStream_t stream) {
  const float* h   = (const float*)d_in[0];
  const int*   adj = (const int*)d_in[1];
  const float* W   = (const float*)d_in[2];
  const float* a   = (const float*)d_in[3];
  float* out = (float*)d_out;

  char* ws = (char*)d_ws;
  // Workspace (~10.2 MB):
  // [0,       +64 KB)  ei
  // [65536,   +64 KB)  ej
  // [131072,  +4 KB)   blockmax (1024 floats, fully written by gat_prep)
  // [135168,  +2 MB)   whB (B-fragment-order Wh, 2M f16 EXACTLY: max index
  //                    ((3*128+127)*4+3)*512+511 = 2,097,151)
  // [2232320, +8 MB)   bits (2M dwords, fully written by gat_pack)
  float*    ei       = (float*)ws;
  float*    ej       = (float*)(ws + 65536);
  float*    blockmax = (float*)(ws + 131072);
  f16*      whB      = (f16*)(ws + 135168);
  uint32_t* bits     = (uint32_t*)(ws + 2232320);

  hipLaunchKernelGGL(gat_pack, dim3(16384), dim3(256), 0, stream, adj, bits);
  hipLaunchKernelGGL(gat_prep, dim3(1024), dim3(256), 0, stream,
                     h, W, a, ei, ej, whB, blockmax);
  hipLaunchKernelGGL(gat_attn, dim3(1024), dim3(512), 0, stream,
                     bits, ei, ej, whB, blockmax, out);
}

// Round 16
// 400.221 us; speedup vs baseline: 1.1138x; 1.0087x over previous
//
#include <hip/hip_runtime.h>
#include <stdint.h>

#define N_NODES 4096
#define F_DIM   64
#define LRELU_ALPHA 0.2f

typedef _Float16 f16;
typedef __attribute__((ext_vector_type(8))) _Float16 half8;  // MFMA f16 A/B frag (4 VGPRs)
typedef __attribute__((ext_vector_type(4))) float f32x4;     // MFMA C/D frag

// ---------------------------------------------------------------------------
// Kernel 0+1 FUSED: prep (blocks 0..1023) + pack (blocks 1024..17407).
// prep and pack are independent; R15 ran them sequentially (~30 + ~45 us).
// Fused with prep blocks FIRST in the grid, prep's VALU/LDS work executes
// under pack's HBM shadow -> ~max instead of sum. Bodies are byte-identical
// to R15's proven kernels; the branch is wave-uniform (blockIdx).
//
// pack: bits[row*128 + (j>>5)] bit (j&31) = adj[row][j] > 0; ballot-based,
//       lane-contiguous 256B/wave-instr, 16 loads in flight.
// prep: Wh = h@W; ei=Wh·a1, ej=Wh·a2; whB in MFMA B-fragment order:
//   whB[((b*128+jc)*4+fc)*512 + (q*16+m)*8 + x] = Wh[j=jc*32+q*8+x][f=fc*16+m]
//       blockmax[blk] = max ej over the block's 16 rows.
// ---------------------------------------------------------------------------
__global__ __launch_bounds__(256) void gat_pp(
    const float* __restrict__ h, const float* __restrict__ W,
    const float* __restrict__ a, const int* __restrict__ adj,
    float* __restrict__ ei, float* __restrict__ ej,
    f16* __restrict__ whB, float* __restrict__ blockmax,
    uint32_t* __restrict__ bits)
{
  __shared__ float sh_h[4][F_DIM];
  __shared__ f16 tile[F_DIM][16];   // [f][loc]
  __shared__ float wmax[4];
  const int t = threadIdx.x, w = t >> 6, lane = t & 63;

  if (blockIdx.x >= 1024) {
    // ---------------- pack role ----------------
    const int r = blockIdx.x - 1024;              // global row (0..16383)
    const int* row = adj + (size_t)r * N_NODES;
    const int jw0 = w * 1024;

    int v[16];
#pragma unroll
    for (int p = 0; p < 16; ++p)
      v[p] = row[jw0 + p * 64 + lane];            // 16 loads in flight

#pragma unroll
    for (int p = 0; p < 16; ++p) {
      const unsigned long long m = __ballot(v[p] > 0);
      if (lane == 0)
        *(uint64_t*)(bits + (size_t)r * 128 + ((jw0 + p * 64) >> 5)) = m;
    }
    return;
  }

  // ---------------- prep role ----------------
  const int n0 = blockIdx.x * 16;       // global row base (0..16383)
  const int b  = n0 >> 12;
  const int nl0 = n0 & (N_NODES - 1);   // row base within batch

  float wcol[F_DIM];
#pragma unroll
  for (int k = 0; k < F_DIM; ++k) wcol[k] = W[k * F_DIM + lane];
  const float a1 = a[lane], a2 = a[F_DIM + lane];

  float runmax = -3e38f;
  for (int r = 0; r < 4; ++r) {
    const int loc = w * 4 + r;
    const int n = n0 + loc;
    const float hv = h[(size_t)n * F_DIM + lane];
    sh_h[w][lane] = hv;                       // same-wave LDS write->read (in-order pipe)
    float wh = 0.f;
#pragma unroll
    for (int k = 0; k < F_DIM; k += 4) {
      const float4 hb = *(const float4*)(&sh_h[w][k]);
      wh = fmaf(hb.x, wcol[k + 0], wh);
      wh = fmaf(hb.y, wcol[k + 1], wh);
      wh = fmaf(hb.z, wcol[k + 2], wh);
      wh = fmaf(hb.w, wcol[k + 3], wh);
    }
    float s1 = wh * a1, s2 = wh * a2;
#pragma unroll
    for (int off = 32; off; off >>= 1) {
      s1 += __shfl_xor(s1, off);
      s2 += __shfl_xor(s2, off);
    }
    if (lane == 0) { ei[n] = s1; ej[n] = s2; }
    runmax = fmaxf(runmax, s2);               // s2 identical on all lanes
    tile[lane][loc] = (f16)wh;                // f = lane
  }
  if (lane == 0) wmax[w] = runmax;
  __syncthreads();

  // B-fragment-order store (coalesced 8-B): jc/q0 fixed per block.
  {
    const int jc = nl0 >> 5;
    const int q0 = (nl0 >> 3) & 3;            // in {0, 2}
    const int fc = t >> 6;
    const int r6 = t & 63;
    const int qp = r6 >> 5;                   // q' in {0,1}
    const int m  = (r6 >> 1) & 15;
    const int xh = (t & 1) * 4;
    const int loc = qp * 8 + xh;              // source loc (+0..3)
    f16* dst = whB + (((size_t)(b * 128 + jc)) * 4 + fc) * 512
                   + ((q0 + qp) * 16 + m) * 8 + xh;
    *(uint2*)dst = *(const uint2*)(&tile[fc * 16 + m][loc]);
  }
  if (t == 0)
    blockmax[blockIdx.x] =
        fmaxf(fmaxf(wmax[0], wmax[1]), fmaxf(wmax[2], wmax[3]));
}

// ---------------------------------------------------------------------------
// Kernel 2: fused masked-softmax attention + PV (f16 MFMA) + ELU, direct out.
// block = (b, 16-row i-tile), 512 threads = 8 waves; wave w sweeps j in
// [w*512, (w+1)*512). bf fragments: lane-contiguous whB loads (1 contiguous
// 1-KB run per instr — the R15 win). Micro-op vs R15: c1 = ei-bnd and
// c2 = 0.2*ei-bnd hoisted; arg = max(ej+c1, fma(0.2,ej,c2)) — one VALU op
// fewer per x, shorter dep chain (logit rounding shifts ~1 ulp, harmless).
// Range control: bnd = leaky(ei + maxej_batch) >= row max logit -> arg <= ~0,
// p' in (0,1], f16-safe; shift cancels in num/den.
// A-frag: A[m=lane&15][k=quad*8+x]; B-frag: B[k=quad*8+x][n=m];
// C/D: row=quad*4+reg, col=lane&15 (HW-verified m89/m91).
// ---------------------------------------------------------------------------
__global__ __launch_bounds__(512, 6) void gat_attn(
    const uint32_t* __restrict__ bits, const float* __restrict__ ei,
    const float* __restrict__ ej, const f16* __restrict__ whB,
    const float* __restrict__ blockmax, float* __restrict__ out)
{
  __shared__ float num_lds[8][16][F_DIM];   // 32 KB
  __shared__ float den_lds[8][16];          // 512 B

  const int t = threadIdx.x, w = t >> 6, lane = t & 63;
  const int quad = lane >> 4, m = lane & 15;
  const int b  = blockIdx.x >> 8;            // 256 i-tiles per batch
  const int i0 = (blockIdx.x & 255) * 16;
  const int i  = i0 + m;
  const int rowg = b * N_NODES + i;

  // per-batch max(ej): reduce 256 plain-stored per-block maxima (L2-hot)
  float maxej;
  {
    const float4 v = *(const float4*)(blockmax + b * 256 + lane * 4);
    maxej = fmaxf(fmaxf(v.x, v.y), fmaxf(v.z, v.w));
#pragma unroll
    for (int off = 32; off; off >>= 1)
      maxej = fmaxf(maxej, __shfl_xor(maxej, off));
  }

  const float ei_s = ei[rowg];
  float bnd = ei_s + maxej;
  bnd = fmaxf(bnd, LRELU_ALPHA * bnd);       // leaky(ei + maxej) >= row max logit
  const float c1 = ei_s - bnd;               // arg = max(ej+c1, 0.2*ej+c2)
  const float c2 = LRELU_ALPHA * ei_s - bnd;

  const float* ejb     = ej + b * N_NODES;
  const uint32_t* bitrow = bits + (size_t)rowg * 128 + w * 16;
  // this wave's fragment base: chunk jc_g = w*16 + jc; 2048 f16 per chunk
  const f16* whw = whB + ((size_t)(b * 128 + w * 16)) * 2048 + lane * 8;

  f32x4 acc[4] = {{0.f,0.f,0.f,0.f},{0.f,0.f,0.f,0.f},
                  {0.f,0.f,0.f,0.f},{0.f,0.f,0.f,0.f}};
  float den = 0.f;
  const int jbase = w * (N_NODES / 8);       // this wave's 512-j window

  for (int jo = 0; jo < 4; ++jo) {
    const uint4 dq = *(const uint4*)(bitrow + jo * 4);
    const uint32_t dws[4] = {dq.x, dq.y, dq.z, dq.w};

#pragma unroll
    for (int ji = 0; ji < 4; ++ji) {
      const int jc = jo * 4 + ji;
      const int jk = jbase + jc * 32 + quad * 8;
      const uint32_t dw = dws[ji];

      float ejA[8];
      *(float4*)(&ejA[0]) = *(const float4*)(ejb + jk);
      *(float4*)(&ejA[4]) = *(const float4*)(ejb + jk + 4);

      const f16* wjc = whw + (size_t)jc * 2048;
      half8 bf[4];
#pragma unroll
      for (int fc = 0; fc < 4; ++fc)
        bf[fc] = *(const half8*)(wjc + fc * 512);

      half8 pa;
#pragma unroll
      for (int x = 0; x < 8; ++x) {
        const float arg = fmaxf(ejA[x] + c1, fmaf(LRELU_ALPHA, ejA[x], c2));
        const float p =
            ((dw >> (quad * 8 + x)) & 1u) ? __expf(arg) : 0.f;
        pa[x] = (f16)p;
        den += (float)pa[x];   // accumulate the SAME quantized value MFMA sees
      }

#pragma unroll
      for (int fc = 0; fc < 4; ++fc)
        acc[fc] = __builtin_amdgcn_mfma_f32_16x16x32_f16(pa, bf[fc], acc[fc], 0, 0, 0);
    }
  }

  // den: lanes sharing a row (same lane&15) live 16 apart
  den += __shfl_xor(den, 16);
  den += __shfl_xor(den, 32);
  if (lane < 16) den_lds[w][lane] = den;

#pragma unroll
  for (int fc = 0; fc < 4; ++fc)
#pragma unroll
    for (int rg = 0; rg < 4; ++rg)
      num_lds[w][quad * 4 + rg][fc * 16 + m] = acc[fc][rg];
  __syncthreads();

  // merge 8 wave-partials, divide, ELU, coalesced store (1024 outs, 512 thr)
#pragma unroll
  for (int k = 0; k < 2; ++k) {
    const int idx = k * 512 + t;
    const int il = idx >> 6, f = idx & 63;
    float num = 0.f, d = 0.f;
#pragma unroll
    for (int ww = 0; ww < 8; ++ww) {
      num += num_lds[ww][il][f];
      d   += den_lds[ww][il];
    }
    float v = (d > 0.f) ? (num / d) : 0.f;
    v = (v > 0.f) ? v : expm1f(v);
    out[((size_t)(b * N_NODES + i0 + il)) * F_DIM + f] = v;
  }
}

extern "C" void kernel_launch(void* const* d_in, const int* in_sizes, int n_in,
                              void* d_out, int out_size, void* d_ws, size_t ws_size,
                              hipStream_t stream) {
  const float* h   = (const float*)d_in[0];
  const int*   adj = (const int*)d_in[1];
  const float* W   = (const float*)d_in[2];
  const float* a   = (const float*)d_in[3];
  float* out = (float*)d_out;

  char* ws = (char*)d_ws;
  // Workspace (~10.2 MB):
  // [0,       +64 KB)  ei
  // [65536,   +64 KB)  ej
  // [131072,  +4 KB)   blockmax (1024 floats, fully written by prep role)
  // [135168,  +2 MB)   whB (B-fragment-order Wh, 2M f16 exactly)
  // [2232320, +8 MB)   bits (2M dwords, fully written by pack role)
  float*    ei       = (float*)ws;
  float*    ej       = (float*)(ws + 65536);
  float*    blockmax = (float*)(ws + 131072);
  f16*      whB      = (f16*)(ws + 135168);
  uint32_t* bits     = (uint32_t*)(ws + 2232320);

  hipLaunchKernelGGL(gat_pp, dim3(17408), dim3(256), 0, stream,
                     h, W, a, adj, ei, ej, whB, blockmax, bits);
  hipLaunchKernelGGL(gat_attn, dim3(1024), dim3(512), 0, stream,
                     bits, ei, ej, whB, blockmax, out);
}

// Round 17
// 392.999 us; speedup vs baseline: 1.1343x; 1.0184x over previous
//
#include <hip/hip_runtime.h>
#include <stdint.h>

#define N_NODES 4096
#define F_DIM   64
#define LRELU_ALPHA 0.2f

typedef _Float16 f16;
typedef __attribute__((ext_vector_type(8))) _Float16 half8;  // MFMA f16 A/B frag (4 VGPRs)
typedef __attribute__((ext_vector_type(4))) float f32x4;     // MFMA C/D frag

// ---------------------------------------------------------------------------
// Kernel 0+1 FUSED, roles INTERLEAVED 1:16 (R16's block-ordered fuse gave no
// overlap: preps filled all CUs first). blockIdx%17==0 -> prep (1024 of
// 17408), else pack (16384). prep's VALU/LDS work rides under pack's HBM
// stream for the whole launch -> ~max instead of sum.
// pack: bits[row*128 + (j>>5)] bit (j&31) = adj[row][j] > 0 (ballot,
//       lane-contiguous 256B/wave-instr, 16 loads in flight).
// prep: Wh = h@W; ei=Wh·a1, ej=Wh·a2; whB in MFMA B-fragment order:
//   whB[((b*128+jc)*4+fc)*512 + (q*16+m)*8 + x] = Wh[j=jc*32+q*8+x][f=fc*16+m]
//       blockmax[pid] = max ej over the prep block's 16 rows.
// ---------------------------------------------------------------------------
__global__ __launch_bounds__(256) void gat_pp(
    const float* __restrict__ h, const float* __restrict__ W,
    const float* __restrict__ a, const int* __restrict__ adj,
    float* __restrict__ ei, float* __restrict__ ej,
    f16* __restrict__ whB, float* __restrict__ blockmax,
    uint32_t* __restrict__ bits)
{
  __shared__ float sh_h[4][F_DIM];
  __shared__ f16 tile[F_DIM][16];   // [f][loc]
  __shared__ float wmax[4];
  const int t = threadIdx.x, w = t >> 6, lane = t & 63;
  const int bid = blockIdx.x;
  const int pid = bid / 17;

  if (bid % 17 != 0) {
    // ---------------- pack role ----------------
    const int r = bid - 1 - pid;                  // pack row (0..16383)
    const int* row = adj + (size_t)r * N_NODES;
    const int jw0 = w * 1024;

    int v[16];
#pragma unroll
    for (int p = 0; p < 16; ++p)
      v[p] = row[jw0 + p * 64 + lane];            // 16 loads in flight

#pragma unroll
    for (int p = 0; p < 16; ++p) {
      const unsigned long long m = __ballot(v[p] > 0);
      if (lane == 0)
        *(uint64_t*)(bits + (size_t)r * 128 + ((jw0 + p * 64) >> 5)) = m;
    }
    return;
  }

  // ---------------- prep role ----------------
  const int n0 = pid * 16;              // global row base (0..16383)
  const int b  = n0 >> 12;
  const int nl0 = n0 & (N_NODES - 1);   // row base within batch

  float wcol[F_DIM];
#pragma unroll
  for (int k = 0; k < F_DIM; ++k) wcol[k] = W[k * F_DIM + lane];
  const float a1 = a[lane], a2 = a[F_DIM + lane];

  float runmax = -3e38f;
  for (int r = 0; r < 4; ++r) {
    const int loc = w * 4 + r;
    const int n = n0 + loc;
    const float hv = h[(size_t)n * F_DIM + lane];
    sh_h[w][lane] = hv;                       // same-wave LDS write->read (in-order pipe)
    float wh = 0.f;
#pragma unroll
    for (int k = 0; k < F_DIM; k += 4) {
      const float4 hb = *(const float4*)(&sh_h[w][k]);
      wh = fmaf(hb.x, wcol[k + 0], wh);
      wh = fmaf(hb.y, wcol[k + 1], wh);
      wh = fmaf(hb.z, wcol[k + 2], wh);
      wh = fmaf(hb.w, wcol[k + 3], wh);
    }
    float s1 = wh * a1, s2 = wh * a2;
#pragma unroll
    for (int off = 32; off; off >>= 1) {
      s1 += __shfl_xor(s1, off);
      s2 += __shfl_xor(s2, off);
    }
    if (lane == 0) { ei[n] = s1; ej[n] = s2; }
    runmax = fmaxf(runmax, s2);               // s2 identical on all lanes
    tile[lane][loc] = (f16)wh;                // f = lane
  }
  if (lane == 0) wmax[w] = runmax;
  __syncthreads();

  // B-fragment-order store (coalesced 8-B): jc/q0 fixed per block.
  {
    const int jc = nl0 >> 5;
    const int q0 = (nl0 >> 3) & 3;            // in {0, 2}
    const int fc = t >> 6;
    const int r6 = t & 63;
    const int qp = r6 >> 5;                   // q' in {0,1}
    const int m  = (r6 >> 1) & 15;
    const int xh = (t & 1) * 4;
    const int loc = qp * 8 + xh;              // source loc (+0..3)
    f16* dst = whB + (((size_t)(b * 128 + jc)) * 4 + fc) * 512
                   + ((q0 + qp) * 16 + m) * 8 + xh;
    *(uint2*)dst = *(const uint2*)(&tile[fc * 16 + m][loc]);
  }
  if (t == 0)
    blockmax[pid] =
        fmaxf(fmaxf(wmax[0], wmax[1]), fmaxf(wmax[2], wmax[3]));
}

// ---------------------------------------------------------------------------
// Kernel 2: attention + PV (f16 MFMA) + ELU. NEW: block = 32 rows (TWO
// 16-row i-tiles), 512 thr = 8 waves; wave w sweeps j in [w*512,(w+1)*512)
// computing pa for BOTH tiles against ONE bf/ejA load -> whB L2 traffic and
// fragment-load instructions halved per unit work (whB 512 MB -> 256 MB/
// launch; R15 showed this path is the binding resource). grid 512 = 2
// blocks/CU (LDS 65 KB/block caps at 2 anyway).
// Range control per tile: bnd = leaky(ei + maxej_batch) >= row max (leaky
// monotone); arg = max(ej+c1, fma(0.2,ej,c2)) <= 0 -> p in (0,1], f16-safe;
// shift cancels in num/den.
// A-frag: A[m=lane&15][k=quad*8+x]; B-frag: B[k=quad*8+x][n=m];
// C/D: row=quad*4+reg, col=lane&15 (HW-verified m89/m91).
// ---------------------------------------------------------------------------
__global__ __launch_bounds__(512, 4) void gat_attn(
    const uint32_t* __restrict__ bits, const float* __restrict__ ei,
    const float* __restrict__ ej, const f16* __restrict__ whB,
    const float* __restrict__ blockmax, float* __restrict__ out)
{
  __shared__ float num_lds[8][32][F_DIM];   // 64 KB
  __shared__ float den_lds[8][32];          // 1 KB

  const int t = threadIdx.x, w = t >> 6, lane = t & 63;
  const int quad = lane >> 4, m = lane & 15;
  const int b  = blockIdx.x >> 7;            // 128 32-row chunks per batch
  const int i0 = (blockIdx.x & 127) * 32;
  const int rowg0 = b * N_NODES + i0 + m;        // tile 0 row
  const int rowg1 = rowg0 + 16;                  // tile 1 row

  // per-batch max(ej): reduce 256 plain-stored per-block maxima (L2-hot)
  float maxej;
  {
    const float4 v = *(const float4*)(blockmax + b * 256 + lane * 4);
    maxej = fmaxf(fmaxf(v.x, v.y), fmaxf(v.z, v.w));
#pragma unroll
    for (int off = 32; off; off >>= 1)
      maxej = fmaxf(maxej, __shfl_xor(maxej, off));
  }

  const float ei0 = ei[rowg0], ei1 = ei[rowg1];
  float bnd0 = ei0 + maxej;
  bnd0 = fmaxf(bnd0, LRELU_ALPHA * bnd0);
  float bnd1 = ei1 + maxej;
  bnd1 = fmaxf(bnd1, LRELU_ALPHA * bnd1);
  const float c10 = ei0 - bnd0, c20 = LRELU_ALPHA * ei0 - bnd0;
  const float c11 = ei1 - bnd1, c21 = LRELU_ALPHA * ei1 - bnd1;

  const float* ejb = ej + b * N_NODES;
  const uint32_t* bitrow0 = bits + (size_t)rowg0 * 128 + w * 16;
  const uint32_t* bitrow1 = bits + (size_t)rowg1 * 128 + w * 16;
  const f16* whw = whB + ((size_t)(b * 128 + w * 16)) * 2048 + lane * 8;

  f32x4 acc0[4] = {{0.f,0.f,0.f,0.f},{0.f,0.f,0.f,0.f},
                   {0.f,0.f,0.f,0.f},{0.f,0.f,0.f,0.f}};
  f32x4 acc1[4] = {{0.f,0.f,0.f,0.f},{0.f,0.f,0.f,0.f},
                   {0.f,0.f,0.f,0.f},{0.f,0.f,0.f,0.f}};
  float den0 = 0.f, den1 = 0.f;
  const int jbase = w * (N_NODES / 8);       // this wave's 512-j window

  for (int jo = 0; jo < 4; ++jo) {
    const uint4 dq0 = *(const uint4*)(bitrow0 + jo * 4);
    const uint4 dq1 = *(const uint4*)(bitrow1 + jo * 4);
    const uint32_t dws0[4] = {dq0.x, dq0.y, dq0.z, dq0.w};
    const uint32_t dws1[4] = {dq1.x, dq1.y, dq1.z, dq1.w};

#pragma unroll
    for (int ji = 0; ji < 4; ++ji) {
      const int jc = jo * 4 + ji;
      const int jk = jbase + jc * 32 + quad * 8;
      const uint32_t dw0 = dws0[ji], dw1 = dws1[ji];

      float ejA[8];
      *(float4*)(&ejA[0]) = *(const float4*)(ejb + jk);
      *(float4*)(&ejA[4]) = *(const float4*)(ejb + jk + 4);

      const f16* wjc = whw + (size_t)jc * 2048;
      half8 bf[4];
#pragma unroll
      for (int fc = 0; fc < 4; ++fc)
        bf[fc] = *(const half8*)(wjc + fc * 512);

      half8 pa0, pa1;
#pragma unroll
      for (int x = 0; x < 8; ++x) {
        const float e = ejA[x];
        const float g0 = fmaxf(e + c10, fmaf(LRELU_ALPHA, e, c20));
        const float g1 = fmaxf(e + c11, fmaf(LRELU_ALPHA, e, c21));
        const float p0 = ((dw0 >> (quad * 8 + x)) & 1u) ? __expf(g0) : 0.f;
        const float p1 = ((dw1 >> (quad * 8 + x)) & 1u) ? __expf(g1) : 0.f;
        pa0[x] = (f16)p0;
        pa1[x] = (f16)p1;
        den0 += (float)pa0[x];
        den1 += (float)pa1[x];
      }

#pragma unroll
      for (int fc = 0; fc < 4; ++fc) {
        acc0[fc] = __builtin_amdgcn_mfma_f32_16x16x32_f16(pa0, bf[fc], acc0[fc], 0, 0, 0);
        acc1[fc] = __builtin_amdgcn_mfma_f32_16x16x32_f16(pa1, bf[fc], acc1[fc], 0, 0, 0);
      }
    }
  }

  // den: lanes sharing a row (same lane&15) live 16 apart
  den0 += __shfl_xor(den0, 16);
  den0 += __shfl_xor(den0, 32);
  den1 += __shfl_xor(den1, 16);
  den1 += __shfl_xor(den1, 32);
  if (lane < 16) {
    den_lds[w][lane] = den0;
    den_lds[w][lane + 16] = den1;
  }

#pragma unroll
  for (int fc = 0; fc < 4; ++fc)
#pragma unroll
    for (int rg = 0; rg < 4; ++rg) {
      num_lds[w][quad * 4 + rg][fc * 16 + m] = acc0[fc][rg];
      num_lds[w][16 + quad * 4 + rg][fc * 16 + m] = acc1[fc][rg];
    }
  __syncthreads();

  // merge 8 wave-partials, divide, ELU, coalesced store (2048 outs, 512 thr)
#pragma unroll
  for (int k = 0; k < 4; ++k) {
    const int idx = k * 512 + t;
    const int il = idx >> 6, f = idx & 63;
    float num = 0.f, d = 0.f;
#pragma unroll
    for (int ww = 0; ww < 8; ++ww) {
      num += num_lds[ww][il][f];
      d   += den_lds[ww][il];
    }
    float v = (d > 0.f) ? (num / d) : 0.f;
    v = (v > 0.f) ? v : expm1f(v);
    out[((size_t)(b * N_NODES + i0 + il)) * F_DIM + f] = v;
  }
}

extern "C" void kernel_launch(void* const* d_in, const int* in_sizes, int n_in,
                              void* d_out, int out_size, void* d_ws, size_t ws_size,
                              hipStream_t stream) {
  const float* h   = (const float*)d_in[0];
  const int*   adj = (const int*)d_in[1];
  const float* W   = (const float*)d_in[2];
  const float* a   = (const float*)d_in[3];
  float* out = (float*)d_out;

  char* ws = (char*)d_ws;
  // Workspace (~10.2 MB):
  // [0,       +64 KB)  ei
  // [65536,   +64 KB)  ej
  // [131072,  +4 KB)   blockmax (1024 floats, fully written by prep role)
  // [135168,  +2 MB)   whB (B-fragment-order Wh, 2M f16 exactly)
  // [2232320, +8 MB)   bits (2M dwords, fully written by pack role)
  float*    ei       = (float*)ws;
  float*    ej       = (float*)(ws + 65536);
  float*    blockmax = (float*)(ws + 131072);
  f16*      whB      = (f16*)(ws + 135168);
  uint32_t* bits     = (uint32_t*)(ws + 2232320);

  hipLaunchKernelGGL(gat_pp, dim3(17408), dim3(256), 0, stream,
                     h, W, a, adj, ei, ej, whB, blockmax, bits);
  hipLaunchKernelGGL(gat_attn, dim3(512), dim3(512), 0, stream,
                     bits, ei, ej, whB, blockmax, out);
}